// Round 11
// baseline (315.931 us; speedup 1.0000x reference)
//
#include <hip/hip_runtime.h>
#include <cstdint>
#include <cstddef>

#define BATCH 2048
#define NZ 128
#define NGEN 8
#define GRPS 32                 // samples per group (same generator)
#define MAXG 72                 // max padded groups
#define NCT 13                  // fc2 col tiles of 128 (12 full + tail 32)
#define H2_ELEMS 1792           // 32*7*8 (x padded 7->8) per sample, bf16
#define WS_H1_OFF 16384
#define WS_H2_OFF (16384 + MAXG * 8192 * 4)              // 2375680
#define WS_W2T_OFF (WS_H2_OFF + BATCH * H2_ELEMS * 2)    // 9715712
#define W2T_GSTRIDE (1568 * 256)                         // fp16 elems per gen
#define NB_W2T (NGEN * 49)                               // 392 transpose blocks

typedef unsigned int u32;
typedef unsigned short u16;
typedef _Float16 f16x8 __attribute__((ext_vector_type(8)));
typedef _Float16 f16x4 __attribute__((ext_vector_type(4)));
typedef float f32x4 __attribute__((ext_vector_type(4)));

__device__ __forceinline__ float lrelu(float x) { return fmaxf(x, 0.2f * x); }
__device__ __forceinline__ float bflo(u32 u) { union { u32 i; float f; } v; v.i = u << 16; return v.f; }
__device__ __forceinline__ float bfhi(u32 u) { union { u32 i; float f; } v; v.i = u & 0xffff0000u; return v.f; }
__device__ __forceinline__ float bf1(u16 u) { union { u32 i; float f; } v; v.i = ((u32)u) << 16; return v.f; }
__device__ __forceinline__ u16 f2bf(float f) {
    union { float f; u32 i; } v; v.f = f;
    u32 r = v.i + 0x7fffu + ((v.i >> 16) & 1u);   // round-to-nearest-even
    return (u16)(r >> 16);
}
__device__ __forceinline__ float fast_tanh(float x) {
    x = fminf(fmaxf(x, -9.f), 9.f);
    const float e = __expf(2.f * x);
    return (e - 1.f) / (e + 1.f);
}

// ---------------------------------------------------------------------------
// Kernel 1: bin samples by generator. wsi[0] = padded total;
// wsi[16..16+tot) = ids grouped by generator, groups padded to 32 with -1.
// ---------------------------------------------------------------------------
__global__ void bin_kernel(const int* __restrict__ g_idx, int* __restrict__ wsi) {
    __shared__ int cnt[NGEN];
    __shared__ int pbase[NGEN + 1];
    __shared__ u16 rank[BATCH];
    const int tid = threadIdx.x;
    if (tid < NGEN) cnt[tid] = 0;
    __syncthreads();
    for (int b = tid; b < BATCH; b += 256) {
        int g = g_idx[b];
        rank[b] = (u16)atomicAdd(&cnt[g], 1);
    }
    __syncthreads();
    if (tid == 0) {
        int acc = 0;
        for (int g = 0; g < NGEN; ++g) {
            pbase[g] = acc;
            acc += ((cnt[g] + GRPS - 1) / GRPS) * GRPS;
        }
        pbase[NGEN] = acc;
        wsi[0] = acc;
    }
    __syncthreads();
    const int total = pbase[NGEN];
    for (int i = tid; i < total; i += 256) wsi[16 + i] = -1;
    __syncthreads();
    for (int b = tid; b < BATCH; b += 256) {
        int g = g_idx[b];
        wsi[16 + pbase[g] + (int)rank[b]] = b;
    }
}

// ---------------------------------------------------------------------------
// Kernel 2: prep = W2 transpose (blocks 0..391) + FC1 (blocks 392..679).
// Both roles depend only on bin's wsi — fused to cut one launch gap.
// ---------------------------------------------------------------------------
__global__ __launch_bounds__(256) void prep_kernel(
    const float* __restrict__ z, const int* __restrict__ g_idx,
    const float* __restrict__ W1, const float* __restrict__ b1,
    const float* __restrict__ W2, const int* __restrict__ wsi,
    float* __restrict__ h1g, _Float16* __restrict__ W2T)
{
    __shared__ _Float16 t[32][264];   // 16.5 KB (w2t role)
    __shared__ float zst[NZ][12];     // 6 KB (fc1 role)
    __shared__ int sb[8];
    __shared__ int sG;

    const int tid = threadIdx.x;
    const int bx = blockIdx.x;

    if (bx < NB_W2T) {
        // ---- W2 transpose role: W2[g][k256][n1568] fp32 -> W2T[g][n][k] fp16
        const int g = bx / 49;
        const int n0 = (bx % 49) * 32;
        const float* src = W2 + (size_t)g * 256 * 1568;
        const int nl = tid & 31, kh = tid >> 5;
        #pragma unroll 8
        for (int p = 0; p < 32; ++p) {
            const int k = p * 8 + kh;
            t[nl][k] = (_Float16)src[(size_t)k * 1568 + n0 + nl];
        }
        __syncthreads();
        _Float16* dst = W2T + (size_t)g * W2T_GSTRIDE + (size_t)n0 * 256;
        const int n = tid >> 3, k0 = (tid & 7) * 32;
        #pragma unroll
        for (int j = 0; j < 4; ++j)
            *(uint4*)(dst + (size_t)n * 256 + k0 + 8 * j) = *(const uint4*)&t[n][k0 + 8 * j];
        return;
    }

    // ---- FC1 role: (group, 8-sample slice); h1g [grp][sample32][col256] fp32
    const int bx2 = bx - NB_W2T;
    const int grp = bx2 >> 2;
    const int s0 = (bx2 & 3) * 8;
    if (grp * GRPS >= wsi[0]) return;

    if (tid == 0) sG = g_idx[wsi[16 + grp * GRPS]];
    if (tid < 8) sb[tid] = wsi[16 + grp * GRPS + s0 + tid];
    __syncthreads();
    const float* W1g = W1 + sG * (NZ * 256);
    const float* b1g = b1 + sG * 256;

    {   // stage z: 8 samples x 128 = 256 float4, one per thread
        const int s = tid >> 5, f = tid & 31;
        float4 v = make_float4(0.f, 0.f, 0.f, 0.f);
        if (sb[s] >= 0) v = *(const float4*)(z + (size_t)sb[s] * NZ + 4 * f);
        zst[4 * f + 0][s] = v.x; zst[4 * f + 1][s] = v.y;
        zst[4 * f + 2][s] = v.z; zst[4 * f + 3][s] = v.w;
    }
    __syncthreads();

    const int c = tid;
    float acc[8];
    #pragma unroll
    for (int s = 0; s < 8; ++s) acc[s] = 0.f;
    const float* wp = W1g + c;
    #pragma unroll 4
    for (int k = 0; k < NZ; ++k) {
        const float w = wp[k * 256];
        float av[8];
        *(float4*)&av[0] = *(const float4*)&zst[k][0];
        *(float4*)&av[4] = *(const float4*)&zst[k][4];
        #pragma unroll
        for (int s = 0; s < 8; ++s) acc[s] += av[s] * w;
    }
    const float bv = b1g[c];
    float* hp = h1g + (size_t)grp * 8192 + (size_t)s0 * 256 + c;
    #pragma unroll
    for (int s = 0; s < 8; ++s) hp[s * 256] = lrelu(acc[s] + bv);
}

// ---------------------------------------------------------------------------
// Kernel 3: FC2 via fp16 MFMA 16x16x32 (unchanged from R10).
// ---------------------------------------------------------------------------
__global__ __launch_bounds__(256) void fc2_kernel(
    const int* __restrict__ g_idx,
    const _Float16* __restrict__ W2T, const float* __restrict__ b2,
    const int* __restrict__ wsi, const float* __restrict__ h1g,
    u16* __restrict__ h2g)
{
    __shared__ _Float16 afrag[2 * 2 * 8 * 64 * 8];   // 32 KB
    __shared__ int sb[GRPS];
    __shared__ int sG;

    const int tid = threadIdx.x;
    const int grp = blockIdx.x / NCT;
    const int tile = blockIdx.x % NCT;
    if (grp * GRPS >= wsi[0]) return;

    if (tid == 0) sG = g_idx[wsi[16 + grp * GRPS]];
    if (tid < GRPS) sb[tid] = wsi[16 + grp * GRPS + tid];
    __syncthreads();
    const _Float16* W2Tg = W2T + (size_t)sG * W2T_GSTRIDE;
    const float* b2g = b2 + sG * 1568;

    {
        const float4* h1p4 = (const float4*)(h1g + (size_t)grp * 8192);
        #pragma unroll
        for (int i = 0; i < 8; ++i) {
            const int id4 = tid + 256 * i;
            const float4 v = h1p4[id4];
            const int s = id4 >> 6;
            const int kk = (id4 & 63) * 4;
            const int lane = ((kk >> 3) & 3) * 16 + (s & 15);
            const int mt = s >> 4, kq = kk >> 5, j = kk & 7;
            const float vv[4] = {v.x, v.y, v.z, v.w};
            f16x4 hi, lo;
            #pragma unroll
            for (int e = 0; e < 4; ++e) {
                hi[e] = (_Float16)vv[e];
                lo[e] = (_Float16)(vv[e] - (float)hi[e]);
            }
            *(f16x4*)&afrag[(((mt * 2 + 0) * 8 + kq) * 64 + lane) * 8 + j] = hi;
            *(f16x4*)&afrag[(((mt * 2 + 1) * 8 + kq) * 64 + lane) * 8 + j] = lo;
        }
    }
    __syncthreads();

    const int wave = tid >> 6;
    const int lane = tid & 63;
    const int q = lane >> 4;
    const int nl = lane & 15;
    const int nb0 = tile * 128 + 2 * wave * 16;
    const int nb1 = nb0 + 16;
    const bool v0 = nb0 < 1568, v1 = nb1 < 1568;
    if (!v0) return;

    const int n0 = nb0 + nl, n1 = nb1 + nl;
    const _Float16* bp0 = W2Tg + (size_t)n0 * 256 + q * 8;
    const _Float16* bp1 = W2Tg + (size_t)n1 * 256 + q * 8;
    f32x4 acc00 = {0.f, 0.f, 0.f, 0.f}, acc10 = acc00, acc01 = acc00, acc11 = acc00;

    #pragma unroll
    for (int kq = 0; kq < 8; ++kq) {
        const f16x8 b0 = *(const f16x8*)(bp0 + kq * 32);
        const f16x8 a0h = *(const f16x8*)&afrag[((0 * 8 + kq) * 64 + lane) * 8];
        const f16x8 a0l = *(const f16x8*)&afrag[((1 * 8 + kq) * 64 + lane) * 8];
        const f16x8 a1h = *(const f16x8*)&afrag[((2 * 8 + kq) * 64 + lane) * 8];
        const f16x8 a1l = *(const f16x8*)&afrag[((3 * 8 + kq) * 64 + lane) * 8];
        acc00 = __builtin_amdgcn_mfma_f32_16x16x32_f16(a0h, b0, acc00, 0, 0, 0);
        acc00 = __builtin_amdgcn_mfma_f32_16x16x32_f16(a0l, b0, acc00, 0, 0, 0);
        acc10 = __builtin_amdgcn_mfma_f32_16x16x32_f16(a1h, b0, acc10, 0, 0, 0);
        acc10 = __builtin_amdgcn_mfma_f32_16x16x32_f16(a1l, b0, acc10, 0, 0, 0);
        if (v1) {
            const f16x8 b1 = *(const f16x8*)(bp1 + kq * 32);
            acc01 = __builtin_amdgcn_mfma_f32_16x16x32_f16(a0h, b1, acc01, 0, 0, 0);
            acc01 = __builtin_amdgcn_mfma_f32_16x16x32_f16(a0l, b1, acc01, 0, 0, 0);
            acc11 = __builtin_amdgcn_mfma_f32_16x16x32_f16(a1h, b1, acc11, 0, 0, 0);
            acc11 = __builtin_amdgcn_mfma_f32_16x16x32_f16(a1l, b1, acc11, 0, 0, 0);
        }
    }

    #pragma unroll
    for (int nt = 0; nt < 2; ++nt) {
        if (nt == 1 && !v1) break;
        const int n = nt ? n1 : n0;
        const float bias = b2g[n];
        const int ci = n / 49, rm = n % 49;
        const int off = ci * 56 + (rm / 7) * 8 + (rm % 7);
        #pragma unroll
        for (int mt = 0; mt < 2; ++mt) {
            const f32x4 a = (nt == 0) ? (mt == 0 ? acc00 : acc10)
                                      : (mt == 0 ? acc01 : acc11);
            #pragma unroll
            for (int reg = 0; reg < 4; ++reg) {
                const int s = mt * 16 + q * 4 + reg;
                const int bb = sb[s];
                if (bb >= 0)
                    h2g[(size_t)bb * H2_ELEMS + off] = f2bf(lrelu(a[reg] + bias));
            }
        }
    }
}

// ---------------------------------------------------------------------------
// conv2 co-PAIR half-pass: one rr load stream serves TWO co rows (halves LDS
// traffic per MAC). Output x in [14*H, 14*H+14) for (co0, co0+1, y).
// ---------------------------------------------------------------------------
template <int H>
__device__ __forceinline__ void conv2_pair(
    const float (*c1s)[14][20], u16 (*c2s)[28][30],
    const float* cw2g, const float bv0, const float bv1,
    const int co0, const int y)
{
    float acc[2][14];
    #pragma unroll
    for (int xx = 0; xx < 14; ++xx) { acc[0][xx] = bv0; acc[1][xx] = bv1; }
    const int a0 = (y + 1) & 1;
    for (int aa = 0; aa < 2; ++aa) {
        const int a = a0 + 2 * aa;
        const int iy = (y + 1 - a) >> 1;
        if ((unsigned)iy < 14u) {
            for (int ci = 0; ci < 16; ++ci) {
                float rr[12];
                if (H == 0) {
                    *(float4*)&rr[0] = *(const float4*)&c1s[ci][iy][0];
                    *(float4*)&rr[4] = *(const float4*)&c1s[ci][iy][4];
                } else {
                    *(float4*)&rr[0] = *(const float4*)&c1s[ci][iy][4];
                    *(float4*)&rr[4] = *(const float4*)&c1s[ci][iy][8];
                    *(float4*)&rr[8] = *(const float4*)&c1s[ci][iy][12];
                }
                const float4 w40 = *(const float4*)(cw2g + ci * 128 + co0 * 16 + a * 4);
                const float4 w41 = *(const float4*)(cw2g + ci * 128 + (co0 + 1) * 16 + a * 4);
                const float wv0[4] = {w40.x, w40.y, w40.z, w40.w};
                const float wv1[4] = {w41.x, w41.y, w41.z, w41.w};
                #pragma unroll
                for (int xx = 0; xx < 14; ++xx) {
                    const int x = 14 * H + xx;
                    const int c0v = (x + 1) & 1;
                    const int ix0 = (x + 1 - c0v) >> 1;
                    const int li = ix0 - 4 * H;            // compile-time
                    if (ix0 < 14) {
                        acc[0][xx] += rr[li] * wv0[c0v];
                        acc[1][xx] += rr[li] * wv1[c0v];
                    }
                    if (ix0 >= 1) {
                        acc[0][xx] += rr[li - 1] * wv0[c0v + 2];
                        acc[1][xx] += rr[li - 1] * wv1[c0v + 2];
                    }
                }
            }
        }
    }
    #pragma unroll
    for (int cc = 0; cc < 2; ++cc) {
        u32* dst = (u32*)&c2s[co0 + cc][y][0];
        #pragma unroll
        for (int xx = 0; xx < 7; ++xx) {
            const u32 lo = f2bf(lrelu(acc[cc][2 * xx]));
            const u32 hi = f2bf(lrelu(acc[cc][2 * xx + 1]));
            dst[7 * H + xx] = lo | (hi << 16);
        }
    }
}

// ---------------------------------------------------------------------------
// Kernel 4: all three transposed convs, ONE sample per block.
// conv1: co-paired (112 threads, full x) — halves h2s LDS reads.
// conv2: co-paired + x-halves (224 threads) — halves c1s LDS reads.
// LDS aliasing: c2s over dead h2s. ~31.4 KB, 5 blocks/CU.
// ---------------------------------------------------------------------------
__global__ __launch_bounds__(256, 5) void conv_kernel(
    const int* __restrict__ g_idx,
    const float* __restrict__ cw1, const float* __restrict__ cb1,
    const float* __restrict__ cw2, const float* __restrict__ cb2,
    const float* __restrict__ cw3, const float* __restrict__ cb3,
    const u16* __restrict__ h2g, float* __restrict__ out)
{
    __shared__ __align__(16) char smem[13440 + 17920];
    float (*h2s)[7][8]   = (float (*)[7][8])smem;            // [32][7][8]
    u16  (*c2s)[28][30]  = (u16 (*)[28][30])smem;            // [8][28][30]
    float (*c1s)[14][20] = (float (*)[14][20])(smem + 13440);
    __shared__ float w3s[72];

    const int tid = threadIdx.x;
    const int b = blockIdx.x;
    const int g = g_idx[b];
    const float* cw1g = cw1 + g * 8192;
    const float* cb1g = cb1 + g * 16;
    const float* cw2g = cw2 + g * 2048;
    const float* cb2g = cb2 + g * 8;
    const float* cw3g = cw3 + g * 72;
    const float  cb3v = cb3[g];

    if (tid < 224) {
        const uint4 qv = ((const uint4*)(h2g + (size_t)b * H2_ELEMS))[tid];
        float* hp = (float*)h2s + 8 * tid;
        ((float4*)hp)[0] = make_float4(bflo(qv.x), bfhi(qv.x), bflo(qv.y), bfhi(qv.y));
        ((float4*)hp)[1] = make_float4(bflo(qv.z), bfhi(qv.z), bflo(qv.w), bfhi(qv.w));
    }
    if (tid < 72) w3s[tid] = cw3g[tid];
    __syncthreads();

    // conv1: [32,7,7] -> [16,14,14], k=4, s=2 — co-paired, 112 threads
    if (tid < 112) {
        const int co0 = 2 * (tid / 14), y = tid % 14;
        float acc[2][14];
        const float bv0 = cb1g[co0], bv1 = cb1g[co0 + 1];
        #pragma unroll
        for (int x = 0; x < 14; ++x) { acc[0][x] = bv0; acc[1][x] = bv1; }
        const int a0 = (y + 1) & 1;
        for (int aa = 0; aa < 2; ++aa) {
            const int a = a0 + 2 * aa;
            const int iy = (y + 1 - a) >> 1;
            if ((unsigned)iy < 7u) {
                for (int ci = 0; ci < 32; ++ci) {
                    float rr[8];
                    *(float4*)&rr[0] = *(const float4*)&h2s[ci][iy][0];
                    *(float4*)&rr[4] = *(const float4*)&h2s[ci][iy][4];
                    const float4 w40 = *(const float4*)(cw1g + ci * 256 + co0 * 16 + a * 4);
                    const float4 w41 = *(const float4*)(cw1g + ci * 256 + (co0 + 1) * 16 + a * 4);
                    const float wv0[4] = {w40.x, w40.y, w40.z, w40.w};
                    const float wv1[4] = {w41.x, w41.y, w41.z, w41.w};
                    #pragma unroll
                    for (int x = 0; x < 14; ++x) {
                        const int c0v = (x + 1) & 1;
                        const int ix0 = (x + 1 - c0v) >> 1;
                        if (ix0 < 7) {
                            acc[0][x] += rr[ix0] * wv0[c0v];
                            acc[1][x] += rr[ix0] * wv1[c0v];
                        }
                        if (ix0 >= 1) {
                            acc[0][x] += rr[ix0 - 1] * wv0[c0v + 2];
                            acc[1][x] += rr[ix0 - 1] * wv1[c0v + 2];
                        }
                    }
                }
            }
        }
        #pragma unroll
        for (int cc = 0; cc < 2; ++cc) {
            float av[14];
            #pragma unroll
            for (int x = 0; x < 14; ++x) av[x] = lrelu(acc[cc][x]);
            *(float4*)&c1s[co0 + cc][y][0]  = *(float4*)&av[0];
            *(float4*)&c1s[co0 + cc][y][4]  = *(float4*)&av[4];
            *(float4*)&c1s[co0 + cc][y][8]  = *(float4*)&av[8];
            *(float2*)&c1s[co0 + cc][y][12] = *(float2*)&av[12];
        }
    }
    __syncthreads();   // h2s dead; c2s may be written

    // conv2: [16,14,14] -> [8,28,28] — co-paired + x-halves, 224 threads
    if (tid < 224) {
        const int y = tid % 28;
        const int cg = tid / 28;          // 0..7
        const int co0 = 2 * (cg & 3);
        const float bv0 = cb2g[co0], bv1 = cb2g[co0 + 1];
        if (cg < 4) conv2_pair<0>(c1s, c2s, cw2g, bv0, bv1, co0, y);
        else        conv2_pair<1>(c1s, c2s, cw2g, bv0, bv1, co0, y);
    }
    __syncthreads();

    // conv3: [8,28,28] -> [1,28,28], k=3, s=1, tanh
    if (tid < 196) {
        const int y = tid / 7, qq = tid % 7;
        const int xb = qq * 4;
        float acc[4] = {cb3v, cb3v, cb3v, cb3v};
        for (int ci = 0; ci < 8; ++ci) {
            float wv[9];
            #pragma unroll
            for (int j = 0; j < 9; ++j) wv[j] = w3s[ci * 9 + j];
            #pragma unroll
            for (int a = 0; a < 3; ++a) {
                const int iy = y + 1 - a;
                if ((unsigned)iy < 28u) {
                    float rr[6];
                    #pragma unroll
                    for (int j = 0; j < 6; ++j) {
                        const int ix = xb - 1 + j;
                        rr[j] = ((unsigned)ix < 28u) ? bf1(c2s[ci][iy][ix]) : 0.f;
                    }
                    #pragma unroll
                    for (int xx = 0; xx < 4; ++xx)
                        #pragma unroll
                        for (int c = 0; c < 3; ++c)
                            acc[xx] += rr[xx + 2 - c] * wv[a * 3 + c];
                }
            }
        }
        float* op = out + (size_t)b * 784 + y * 28 + xb;
        #pragma unroll
        for (int xx = 0; xx < 4; ++xx) op[xx] = fast_tanh(acc[xx]);
    }
}

extern "C" void kernel_launch(void* const* d_in, const int* in_sizes, int n_in,
                              void* d_out, int out_size, void* d_ws, size_t ws_size,
                              hipStream_t stream) {
    const float* z   = (const float*)d_in[0];
    const int*   gi  = (const int*)d_in[1];
    const float* W1  = (const float*)d_in[2];
    const float* b1  = (const float*)d_in[3];
    const float* W2  = (const float*)d_in[4];
    const float* b2  = (const float*)d_in[5];
    const float* cw1 = (const float*)d_in[6];
    const float* cb1 = (const float*)d_in[7];
    const float* cw2 = (const float*)d_in[8];
    const float* cb2 = (const float*)d_in[9];
    const float* cw3 = (const float*)d_in[10];
    const float* cb3 = (const float*)d_in[11];
    int*      wsi = (int*)d_ws;
    float*    h1g = (float*)((char*)d_ws + WS_H1_OFF);
    u16*      h2g = (u16*)((char*)d_ws + WS_H2_OFF);
    _Float16* w2t = (_Float16*)((char*)d_ws + WS_W2T_OFF);

    bin_kernel<<<1, 256, 0, stream>>>(gi, wsi);
    prep_kernel<<<NB_W2T + MAXG * 4, 256, 0, stream>>>(z, gi, W1, b1, W2, wsi, h1g, w2t);
    fc2_kernel<<<MAXG * NCT, 256, 0, stream>>>(gi, w2t, b2, wsi, h1g, h2g);
    conv_kernel<<<BATCH, 256, 0, stream>>>(gi, cw1, cb1, cw2, cb2, cw3, cb3,
                                           h2g, (float*)d_out);
}

// Round 12
// 218.919 us; speedup vs baseline: 1.4431x; 1.4431x over previous
//
#include <hip/hip_runtime.h>
#include <cstdint>
#include <cstddef>

#define BATCH 2048
#define NZ 128
#define NGEN 8
#define GRPS 32                 // samples per group (same generator)
#define MAXG 72                 // max padded groups
#define NCT 13                  // fc2 col tiles of 128 (12 full + tail 32)
#define H2_ELEMS 1792           // 32*7*8 (x padded 7->8) per sample, bf16
#define WS_H1_OFF 16384                                  // h1: 2048*256 fp32 = 2 MB
#define WS_H2_OFF (WS_H1_OFF + BATCH * 256 * 4)          // 2113536
#define WS_W2T_OFF (WS_H2_OFF + BATCH * H2_ELEMS * 2)    // 9453568
#define W2T_GSTRIDE (1568 * 256)                         // fp16 elems per gen
#define NB_BIN 8
#define NB_W2T (NGEN * 49)                               // 392
#define NB_FC1 (BATCH / 8)                               // 256

typedef unsigned int u32;
typedef unsigned short u16;
typedef _Float16 f16x8 __attribute__((ext_vector_type(8)));
typedef _Float16 f16x4 __attribute__((ext_vector_type(4)));
typedef float f32x4 __attribute__((ext_vector_type(4)));

__device__ __forceinline__ float lrelu(float x) { return fmaxf(x, 0.2f * x); }
__device__ __forceinline__ float bflo(u32 u) { union { u32 i; float f; } v; v.i = u << 16; return v.f; }
__device__ __forceinline__ float bfhi(u32 u) { union { u32 i; float f; } v; v.i = u & 0xffff0000u; return v.f; }
__device__ __forceinline__ float bf1(u16 u) { union { u32 i; float f; } v; v.i = ((u32)u) << 16; return v.f; }
__device__ __forceinline__ u16 f2bf(float f) {
    union { float f; u32 i; } v; v.f = f;
    u32 r = v.i + 0x7fffu + ((v.i >> 16) & 1u);   // round-to-nearest-even
    return (u16)(r >> 16);
}
__device__ __forceinline__ float fast_tanh(float x) {
    x = fminf(fmaxf(x, -9.f), 9.f);
    const float e = __expf(2.f * x);
    return (e - 1.f) / (e + 1.f);
}

// ---------------------------------------------------------------------------
// Kernel 1: prep — three block roles, all depending only on raw inputs:
//   [0,8):    bin, one block per generator g: wsi[16..] group lists (pad -1)
//   [8,400):  W2 transpose fp32[k][n] -> fp16[n][k]
//   [400,656): FC1 natural order, 8 samples/block, per-sample generator
// ---------------------------------------------------------------------------
__global__ __launch_bounds__(256) void prep_kernel(
    const float* __restrict__ z, const int* __restrict__ g_idx,
    const float* __restrict__ W1, const float* __restrict__ b1,
    const float* __restrict__ W2, int* __restrict__ wsi,
    float* __restrict__ h1g, _Float16* __restrict__ W2T)
{
    __shared__ _Float16 t[32][264];   // w2t role, 16.5 KB
    __shared__ float zs[8][128];      // fc1 role, 4 KB
    __shared__ int gsh[8];
    __shared__ int cnts[NGEN];        // bin role
    __shared__ int tc[257];
    __shared__ int sBase, sPcnt;

    const int tid = threadIdx.x;
    const int bx = blockIdx.x;

    if (bx < NB_BIN) {
        // ---- bin role: this block owns generator gb ----
        const int gb = bx;
        if (tid < NGEN) cnts[tid] = 0;
        __syncthreads();
        int loc[8];
        int lc = 0;
        #pragma unroll
        for (int j = 0; j < 8; ++j) {
            const int b = tid * 8 + j;
            const int g = g_idx[b];
            atomicAdd(&cnts[g], 1);
            if (g == gb) loc[lc++] = b;
        }
        tc[tid] = lc;
        __syncthreads();
        if (tid == 0) {
            int a = 0, basev = 0;
            for (int g = 0; g < NGEN; ++g) {
                if (g == gb) basev = a;
                a += ((cnts[g] + GRPS - 1) / GRPS) * GRPS;
            }
            sBase = basev;
            sPcnt = ((cnts[gb] + GRPS - 1) / GRPS) * GRPS;
            if (gb == 0) wsi[0] = a;
            int pr = 0;
            for (int i = 0; i < 256; ++i) { const int c = tc[i]; tc[i] = pr; pr += c; }
            tc[256] = pr;   // = cnts[gb]
        }
        __syncthreads();
        const int base = sBase;
        const int pos = base + tc[tid];
        for (int j = 0; j < lc; ++j) wsi[16 + pos + j] = loc[j];
        for (int i = tc[256] + tid; i < sPcnt; i += 256) wsi[16 + base + i] = -1;
        return;
    }

    if (bx < NB_BIN + NB_W2T) {
        // ---- W2 transpose role ----
        const int bt = bx - NB_BIN;
        const int g = bt / 49;
        const int n0 = (bt % 49) * 32;
        const float* src = W2 + (size_t)g * 256 * 1568;
        const int nl = tid & 31, kh = tid >> 5;
        #pragma unroll 8
        for (int p = 0; p < 32; ++p) {
            const int k = p * 8 + kh;
            t[nl][k] = (_Float16)src[(size_t)k * 1568 + n0 + nl];
        }
        __syncthreads();
        _Float16* dst = W2T + (size_t)g * W2T_GSTRIDE + (size_t)n0 * 256;
        const int n = tid >> 3, k0 = (tid & 7) * 32;
        #pragma unroll
        for (int j = 0; j < 4; ++j)
            *(uint4*)(dst + (size_t)n * 256 + k0 + 8 * j) = *(const uint4*)&t[n][k0 + 8 * j];
        return;
    }

    // ---- FC1 role: natural order, samples s0..s0+7 ----
    const int s0 = (bx - NB_BIN - NB_W2T) * 8;
    {
        const int s = tid >> 5, f = tid & 31;
        const float4 v = *(const float4*)(z + (size_t)(s0 + s) * NZ + 4 * f);
        zs[s][4 * f + 0] = v.x; zs[s][4 * f + 1] = v.y;
        zs[s][4 * f + 2] = v.z; zs[s][4 * f + 3] = v.w;
    }
    if (tid < 8) gsh[tid] = g_idx[s0 + tid];
    __syncthreads();

    const int c = tid;
    #pragma unroll
    for (int ss = 0; ss < 8; ++ss) {
        const int g = gsh[ss];
        const float* wp = W1 + (size_t)g * (NZ * 256) + c;
        float a = 0.f;
        #pragma unroll 4
        for (int k = 0; k < NZ; ++k) a += zs[ss][k] * wp[k * 256];
        h1g[(size_t)(s0 + ss) * 256 + c] = lrelu(a + b1[g * 256 + c]);
    }
}

// ---------------------------------------------------------------------------
// Kernel 2: FC2 via fp16 MFMA 16x16x32. Block = (group, 128-col tile).
// A = h1 (gathered via sb, natural layout) split hi+lo fp16, frag-ordered LDS;
// B = W2T fp16, one aligned 16 B load per fragment. D fp32.
// C/D layout: col(n)=lane&15, row(m)=(lane>>4)*4+reg [m89].
// ---------------------------------------------------------------------------
__global__ __launch_bounds__(256) void fc2_kernel(
    const int* __restrict__ g_idx,
    const _Float16* __restrict__ W2T, const float* __restrict__ b2,
    const int* __restrict__ wsi, const float* __restrict__ h1g,
    u16* __restrict__ h2g)
{
    __shared__ _Float16 afrag[2 * 2 * 8 * 64 * 8];   // 32 KB
    __shared__ int sb[GRPS];
    __shared__ int sG;

    const int tid = threadIdx.x;
    const int grp = blockIdx.x / NCT;
    const int tile = blockIdx.x % NCT;
    if (grp * GRPS >= wsi[0]) return;

    if (tid == 0) sG = g_idx[wsi[16 + grp * GRPS]];
    if (tid < GRPS) sb[tid] = wsi[16 + grp * GRPS + tid];
    __syncthreads();
    const _Float16* W2Tg = W2T + (size_t)sG * W2T_GSTRIDE;
    const float* b2g = b2 + sG * 1568;

    {   // stage A fragments (hi/lo split); gather rows via sb
        const float4* h1p4 = (const float4*)h1g;
        #pragma unroll
        for (int i = 0; i < 8; ++i) {
            const int id4 = tid + 256 * i;
            const int s = id4 >> 6;
            const int bb = sb[s];
            float4 v = make_float4(0.f, 0.f, 0.f, 0.f);
            if (bb >= 0) v = h1p4[(size_t)bb * 64 + (id4 & 63)];
            const int kk = (id4 & 63) * 4;
            const int lane = ((kk >> 3) & 3) * 16 + (s & 15);
            const int mt = s >> 4, kq = kk >> 5, j = kk & 7;
            const float vv[4] = {v.x, v.y, v.z, v.w};
            f16x4 hi, lo;
            #pragma unroll
            for (int e = 0; e < 4; ++e) {
                hi[e] = (_Float16)vv[e];
                lo[e] = (_Float16)(vv[e] - (float)hi[e]);
            }
            *(f16x4*)&afrag[(((mt * 2 + 0) * 8 + kq) * 64 + lane) * 8 + j] = hi;
            *(f16x4*)&afrag[(((mt * 2 + 1) * 8 + kq) * 64 + lane) * 8 + j] = lo;
        }
    }
    __syncthreads();

    const int wave = tid >> 6;
    const int lane = tid & 63;
    const int q = lane >> 4;
    const int nl = lane & 15;
    const int nb0 = tile * 128 + 2 * wave * 16;
    const int nb1 = nb0 + 16;
    const bool v0 = nb0 < 1568, v1 = nb1 < 1568;
    if (!v0) return;

    const int n0 = nb0 + nl, n1 = nb1 + nl;
    const _Float16* bp0 = W2Tg + (size_t)n0 * 256 + q * 8;
    const _Float16* bp1 = W2Tg + (size_t)n1 * 256 + q * 8;
    f32x4 acc00 = {0.f, 0.f, 0.f, 0.f}, acc10 = acc00, acc01 = acc00, acc11 = acc00;

    #pragma unroll
    for (int kq = 0; kq < 8; ++kq) {
        const f16x8 b0 = *(const f16x8*)(bp0 + kq * 32);
        const f16x8 a0h = *(const f16x8*)&afrag[((0 * 8 + kq) * 64 + lane) * 8];
        const f16x8 a0l = *(const f16x8*)&afrag[((1 * 8 + kq) * 64 + lane) * 8];
        const f16x8 a1h = *(const f16x8*)&afrag[((2 * 8 + kq) * 64 + lane) * 8];
        const f16x8 a1l = *(const f16x8*)&afrag[((3 * 8 + kq) * 64 + lane) * 8];
        acc00 = __builtin_amdgcn_mfma_f32_16x16x32_f16(a0h, b0, acc00, 0, 0, 0);
        acc00 = __builtin_amdgcn_mfma_f32_16x16x32_f16(a0l, b0, acc00, 0, 0, 0);
        acc10 = __builtin_amdgcn_mfma_f32_16x16x32_f16(a1h, b0, acc10, 0, 0, 0);
        acc10 = __builtin_amdgcn_mfma_f32_16x16x32_f16(a1l, b0, acc10, 0, 0, 0);
        if (v1) {
            const f16x8 b1 = *(const f16x8*)(bp1 + kq * 32);
            acc01 = __builtin_amdgcn_mfma_f32_16x16x32_f16(a0h, b1, acc01, 0, 0, 0);
            acc01 = __builtin_amdgcn_mfma_f32_16x16x32_f16(a0l, b1, acc01, 0, 0, 0);
            acc11 = __builtin_amdgcn_mfma_f32_16x16x32_f16(a1h, b1, acc11, 0, 0, 0);
            acc11 = __builtin_amdgcn_mfma_f32_16x16x32_f16(a1l, b1, acc11, 0, 0, 0);
        }
    }

    #pragma unroll
    for (int nt = 0; nt < 2; ++nt) {
        if (nt == 1 && !v1) break;
        const int n = nt ? n1 : n0;
        const float bias = b2g[n];
        const int ci = n / 49, rm = n % 49;
        const int off = ci * 56 + (rm / 7) * 8 + (rm % 7);
        #pragma unroll
        for (int mt = 0; mt < 2; ++mt) {
            const f32x4 a = (nt == 0) ? (mt == 0 ? acc00 : acc10)
                                      : (mt == 0 ? acc01 : acc11);
            #pragma unroll
            for (int reg = 0; reg < 4; ++reg) {
                const int s = mt * 16 + q * 4 + reg;
                const int bb = sb[s];
                if (bb >= 0)
                    h2g[(size_t)bb * H2_ELEMS + off] = f2bf(lrelu(a[reg] + bias));
            }
        }
    }
}

// ---------------------------------------------------------------------------
// conv2 half-pass (R10-proven, unpaired): output x in [14*H, 14*H+14).
// ---------------------------------------------------------------------------
template <int H>
__device__ __forceinline__ void conv2_half(
    const float (*c1s)[14][20], u16 (*c2s)[28][30],
    const float* cw2g, const float bv, const int co, const int y)
{
    float acc[14];
    #pragma unroll
    for (int xx = 0; xx < 14; ++xx) acc[xx] = bv;
    const int a0 = (y + 1) & 1;
    for (int aa = 0; aa < 2; ++aa) {
        const int a = a0 + 2 * aa;
        const int iy = (y + 1 - a) >> 1;
        if ((unsigned)iy < 14u) {
            #pragma unroll 2
            for (int ci = 0; ci < 16; ++ci) {
                float rr[12];
                if (H == 0) {
                    *(float4*)&rr[0] = *(const float4*)&c1s[ci][iy][0];
                    *(float4*)&rr[4] = *(const float4*)&c1s[ci][iy][4];
                } else {
                    *(float4*)&rr[0] = *(const float4*)&c1s[ci][iy][4];
                    *(float4*)&rr[4] = *(const float4*)&c1s[ci][iy][8];
                    *(float4*)&rr[8] = *(const float4*)&c1s[ci][iy][12];
                }
                const float4 w4 = *(const float4*)(cw2g + ci * 128 + co * 16 + a * 4);
                const float wv[4] = {w4.x, w4.y, w4.z, w4.w};
                #pragma unroll
                for (int xx = 0; xx < 14; ++xx) {
                    const int x = 14 * H + xx;
                    const int c0v = (x + 1) & 1;
                    const int ix0 = (x + 1 - c0v) >> 1;
                    const int li = ix0 - 4 * H;
                    if (ix0 < 14) acc[xx] += rr[li] * wv[c0v];
                    if (ix0 >= 1) acc[xx] += rr[li - 1] * wv[c0v + 2];
                }
            }
        }
    }
    u32* dst = (u32*)&c2s[co][y][0];
    #pragma unroll
    for (int xx = 0; xx < 7; ++xx) {
        const u32 lo = f2bf(lrelu(acc[2 * xx]));
        const u32 hi = f2bf(lrelu(acc[2 * xx + 1]));
        dst[7 * H + xx] = lo | (hi << 16);
    }
}

// ---------------------------------------------------------------------------
// Kernel 3: all three transposed convs, ONE sample per block (R10-proven).
// LDS aliasing: c2s over dead h2s. ~31.4 KB, 5 blocks/CU.
// ---------------------------------------------------------------------------
__global__ __launch_bounds__(256, 5) void conv_kernel(
    const int* __restrict__ g_idx,
    const float* __restrict__ cw1, const float* __restrict__ cb1,
    const float* __restrict__ cw2, const float* __restrict__ cb2,
    const float* __restrict__ cw3, const float* __restrict__ cb3,
    const u16* __restrict__ h2g, float* __restrict__ out)
{
    __shared__ __align__(16) char smem[13440 + 17920];
    float (*h2s)[7][8]   = (float (*)[7][8])smem;            // [32][7][8]
    u16  (*c2s)[28][30]  = (u16 (*)[28][30])smem;            // [8][28][30]
    float (*c1s)[14][20] = (float (*)[14][20])(smem + 13440);
    __shared__ float w3s[72];

    const int tid = threadIdx.x;
    const int b = blockIdx.x;
    const int g = g_idx[b];
    const float* cw1g = cw1 + g * 8192;
    const float* cb1g = cb1 + g * 16;
    const float* cw2g = cw2 + g * 2048;
    const float* cb2g = cb2 + g * 8;
    const float* cw3g = cw3 + g * 72;
    const float  cb3v = cb3[g];

    if (tid < 224) {
        const uint4 qv = ((const uint4*)(h2g + (size_t)b * H2_ELEMS))[tid];
        float* hp = (float*)h2s + 8 * tid;
        ((float4*)hp)[0] = make_float4(bflo(qv.x), bfhi(qv.x), bflo(qv.y), bfhi(qv.y));
        ((float4*)hp)[1] = make_float4(bflo(qv.z), bfhi(qv.z), bflo(qv.w), bfhi(qv.w));
    }
    if (tid < 72) w3s[tid] = cw3g[tid];
    __syncthreads();

    // conv1: [32,7,7] -> [16,14,14], k=4, s=2
    if (tid < 224) {
        const int co = tid / 14, y = tid % 14;
        float acc[14];
        const float bv = cb1g[co];
        #pragma unroll
        for (int x = 0; x < 14; ++x) acc[x] = bv;
        const int a0 = (y + 1) & 1;
        for (int aa = 0; aa < 2; ++aa) {
            const int a = a0 + 2 * aa;
            const int iy = (y + 1 - a) >> 1;
            if ((unsigned)iy < 7u) {
                #pragma unroll 2
                for (int ci = 0; ci < 32; ++ci) {
                    float rr[8];
                    *(float4*)&rr[0] = *(const float4*)&h2s[ci][iy][0];
                    *(float4*)&rr[4] = *(const float4*)&h2s[ci][iy][4];
                    const float4 w4 = *(const float4*)(cw1g + ci * 256 + co * 16 + a * 4);
                    const float wv[4] = {w4.x, w4.y, w4.z, w4.w};
                    #pragma unroll
                    for (int x = 0; x < 14; ++x) {
                        const int c0v = (x + 1) & 1;
                        const int ix0 = (x + 1 - c0v) >> 1;
                        if (ix0 < 7)  acc[x] += rr[ix0] * wv[c0v];
                        if (ix0 >= 1) acc[x] += rr[ix0 - 1] * wv[c0v + 2];
                    }
                }
            }
        }
        #pragma unroll
        for (int x = 0; x < 14; ++x) acc[x] = lrelu(acc[x]);
        *(float4*)&c1s[co][y][0]  = *(float4*)&acc[0];
        *(float4*)&c1s[co][y][4]  = *(float4*)&acc[4];
        *(float4*)&c1s[co][y][8]  = *(float4*)&acc[8];
        *(float2*)&c1s[co][y][12] = *(float2*)&acc[12];
    }
    __syncthreads();   // h2s dead; c2s may be written

    if (tid < 224) {
        const int co = tid / 28, y = tid % 28;
        const float bv = cb2g[co];
        conv2_half<0>(c1s, c2s, cw2g, bv, co, y);
        conv2_half<1>(c1s, c2s, cw2g, bv, co, y);
    }
    __syncthreads();

    if (tid < 196) {
        const int y = tid / 7, qq = tid % 7;
        const int xb = qq * 4;
        float acc[4] = {cb3v, cb3v, cb3v, cb3v};
        for (int ci = 0; ci < 8; ++ci) {
            float wv[9];
            #pragma unroll
            for (int j = 0; j < 9; ++j) wv[j] = w3s[ci * 9 + j];
            #pragma unroll
            for (int a = 0; a < 3; ++a) {
                const int iy = y + 1 - a;
                if ((unsigned)iy < 28u) {
                    float rr[6];
                    #pragma unroll
                    for (int j = 0; j < 6; ++j) {
                        const int ix = xb - 1 + j;
                        rr[j] = ((unsigned)ix < 28u) ? bf1(c2s[ci][iy][ix]) : 0.f;
                    }
                    #pragma unroll
                    for (int xx = 0; xx < 4; ++xx)
                        #pragma unroll
                        for (int c = 0; c < 3; ++c)
                            acc[xx] += rr[xx + 2 - c] * wv[a * 3 + c];
                }
            }
        }
        float* op = out + (size_t)b * 784 + y * 28 + xb;
        #pragma unroll
        for (int xx = 0; xx < 4; ++xx) op[xx] = fast_tanh(acc[xx]);
    }
}

extern "C" void kernel_launch(void* const* d_in, const int* in_sizes, int n_in,
                              void* d_out, int out_size, void* d_ws, size_t ws_size,
                              hipStream_t stream) {
    const float* z   = (const float*)d_in[0];
    const int*   gi  = (const int*)d_in[1];
    const float* W1  = (const float*)d_in[2];
    const float* b1  = (const float*)d_in[3];
    const float* W2  = (const float*)d_in[4];
    const float* b2  = (const float*)d_in[5];
    const float* cw1 = (const float*)d_in[6];
    const float* cb1 = (const float*)d_in[7];
    const float* cw2 = (const float*)d_in[8];
    const float* cb2 = (const float*)d_in[9];
    const float* cw3 = (const float*)d_in[10];
    const float* cb3 = (const float*)d_in[11];
    int*      wsi = (int*)d_ws;
    float*    h1g = (float*)((char*)d_ws + WS_H1_OFF);
    u16*      h2g = (u16*)((char*)d_ws + WS_H2_OFF);
    _Float16* w2t = (_Float16*)((char*)d_ws + WS_W2T_OFF);

    prep_kernel<<<NB_BIN + NB_W2T + NB_FC1, 256, 0, stream>>>(
        z, gi, W1, b1, W2, wsi, h1g, w2t);
    fc2_kernel<<<MAXG * NCT, 256, 0, stream>>>(gi, w2t, b2, wsi, h1g, h2g);
    conv_kernel<<<BATCH, 256, 0, stream>>>(gi, cw1, cb1, cw2, cb2, cw3, cb3,
                                           h2g, (float*)d_out);
}

// Round 13
// 198.092 us; speedup vs baseline: 1.5949x; 1.1051x over previous
//
#include <hip/hip_runtime.h>
#include <cstdint>
#include <cstddef>

#define BATCH 2048
#define NZ 128
#define NGEN 8
#define GRPS 32                 // samples per group (same generator)
#define MAXG 72                 // max padded groups
#define NCT 13                  // fc2 col tiles of 128 (12 full + tail 32)
#define H2_ELEMS 1792           // 32*7*8 (x padded 7->8) per sample, bf16
#define WS_H1_OFF 16384                                  // h1: 72*8192 fp32
#define WS_H2_OFF (16384 + MAXG * 8192 * 4)              // 2375680
#define WS_W2T_OFF (WS_H2_OFF + BATCH * H2_ELEMS * 2)    // 9715712
#define W2T_GSTRIDE (1568 * 256)                         // fp16 elems per gen
#define NB_W2T (NGEN * 49)                               // 392

typedef unsigned int u32;
typedef unsigned short u16;
typedef _Float16 f16x8 __attribute__((ext_vector_type(8)));
typedef _Float16 f16x4 __attribute__((ext_vector_type(4)));
typedef float f32x4 __attribute__((ext_vector_type(4)));

__device__ __forceinline__ float lrelu(float x) { return fmaxf(x, 0.2f * x); }
__device__ __forceinline__ float bflo(u32 u) { union { u32 i; float f; } v; v.i = u << 16; return v.f; }
__device__ __forceinline__ float bfhi(u32 u) { union { u32 i; float f; } v; v.i = u & 0xffff0000u; return v.f; }
__device__ __forceinline__ float bf1(u16 u) { union { u32 i; float f; } v; v.i = ((u32)u) << 16; return v.f; }
__device__ __forceinline__ u16 f2bf(float f) {
    union { float f; u32 i; } v; v.f = f;
    u32 r = v.i + 0x7fffu + ((v.i >> 16) & 1u);   // round-to-nearest-even
    return (u16)(r >> 16);
}
__device__ __forceinline__ float fast_tanh(float x) {
    x = fminf(fmaxf(x, -9.f), 9.f);
    const float e = __expf(2.f * x);
    return (e - 1.f) / (e + 1.f);
}

// ---------------------------------------------------------------------------
// Kernel 1: bin samples by generator (R10-proven 1-block form).
// wsi[0] = padded total; wsi[16..] = ids grouped, groups padded to 32 w/ -1.
// ---------------------------------------------------------------------------
__global__ void bin_kernel(const int* __restrict__ g_idx, int* __restrict__ wsi) {
    __shared__ int cnt[NGEN];
    __shared__ int pbase[NGEN + 1];
    __shared__ u16 rank[BATCH];
    const int tid = threadIdx.x;
    if (tid < NGEN) cnt[tid] = 0;
    __syncthreads();
    for (int b = tid; b < BATCH; b += 256) {
        int g = g_idx[b];
        rank[b] = (u16)atomicAdd(&cnt[g], 1);
    }
    __syncthreads();
    if (tid == 0) {
        int acc = 0;
        for (int g = 0; g < NGEN; ++g) {
            pbase[g] = acc;
            acc += ((cnt[g] + GRPS - 1) / GRPS) * GRPS;
        }
        pbase[NGEN] = acc;
        wsi[0] = acc;
    }
    __syncthreads();
    const int total = pbase[NGEN];
    for (int i = tid; i < total; i += 256) wsi[16 + i] = -1;
    __syncthreads();
    for (int b = tid; b < BATCH; b += 256) {
        int g = g_idx[b];
        wsi[16 + pbase[g] + (int)rank[b]] = b;
    }
}

// ---------------------------------------------------------------------------
// Kernel 2: prep = W2 transpose (blocks 0..391) + grouped FC1 (392..679).
// (R11-proven roles; fc1 grouped = one generator per block, W1 reuse x8.)
// h1g layout [grp][sample 32][col 256] fp32 (group-local).
// ---------------------------------------------------------------------------
__global__ __launch_bounds__(256) void prep_kernel(
    const float* __restrict__ z, const int* __restrict__ g_idx,
    const float* __restrict__ W1, const float* __restrict__ b1,
    const float* __restrict__ W2, const int* __restrict__ wsi,
    float* __restrict__ h1g, _Float16* __restrict__ W2T)
{
    __shared__ _Float16 t[32][264];   // w2t role, 16.5 KB
    __shared__ float zst[NZ][12];     // fc1 role, 6 KB
    __shared__ int sb[8];
    __shared__ int sG;

    const int tid = threadIdx.x;
    const int bx = blockIdx.x;

    if (bx < NB_W2T) {
        // ---- W2 transpose role: W2[g][k256][n1568] fp32 -> W2T[g][n][k] fp16
        const int g = bx / 49;
        const int n0 = (bx % 49) * 32;
        const float* src = W2 + (size_t)g * 256 * 1568;
        const int nl = tid & 31, kh = tid >> 5;
        #pragma unroll 8
        for (int p = 0; p < 32; ++p) {
            const int k = p * 8 + kh;
            t[nl][k] = (_Float16)src[(size_t)k * 1568 + n0 + nl];
        }
        __syncthreads();
        _Float16* dst = W2T + (size_t)g * W2T_GSTRIDE + (size_t)n0 * 256;
        const int n = tid >> 3, k0 = (tid & 7) * 32;
        #pragma unroll
        for (int j = 0; j < 4; ++j)
            *(uint4*)(dst + (size_t)n * 256 + k0 + 8 * j) = *(const uint4*)&t[n][k0 + 8 * j];
        return;
    }

    // ---- FC1 role (grouped): (group, 8-sample slice) ----
    const int bx2 = bx - NB_W2T;
    const int grp = bx2 >> 2;
    const int s0 = (bx2 & 3) * 8;
    if (grp * GRPS >= wsi[0]) return;

    if (tid == 0) sG = g_idx[wsi[16 + grp * GRPS]];
    if (tid < 8) sb[tid] = wsi[16 + grp * GRPS + s0 + tid];
    __syncthreads();
    const float* W1g = W1 + sG * (NZ * 256);
    const float* b1g = b1 + sG * 256;

    {   // stage z: 8 samples x 128 = 256 float4, one per thread
        const int s = tid >> 5, f = tid & 31;
        float4 v = make_float4(0.f, 0.f, 0.f, 0.f);
        if (sb[s] >= 0) v = *(const float4*)(z + (size_t)sb[s] * NZ + 4 * f);
        zst[4 * f + 0][s] = v.x; zst[4 * f + 1][s] = v.y;
        zst[4 * f + 2][s] = v.z; zst[4 * f + 3][s] = v.w;
    }
    __syncthreads();

    const int c = tid;
    float acc[8];
    #pragma unroll
    for (int s = 0; s < 8; ++s) acc[s] = 0.f;
    const float* wp = W1g + c;
    #pragma unroll 4
    for (int k = 0; k < NZ; ++k) {
        const float w = wp[k * 256];
        float av[8];
        *(float4*)&av[0] = *(const float4*)&zst[k][0];
        *(float4*)&av[4] = *(const float4*)&zst[k][4];
        #pragma unroll
        for (int s = 0; s < 8; ++s) acc[s] += av[s] * w;
    }
    const float bv = b1g[c];
    float* hp = h1g + (size_t)grp * 8192 + (size_t)s0 * 256 + c;
    #pragma unroll
    for (int s = 0; s < 8; ++s) hp[s * 256] = lrelu(acc[s] + bv);
}

// ---------------------------------------------------------------------------
// Kernel 3: FC2 via fp16 MFMA 16x16x32 — conflict-free staging + split-pass.
// Staging map: u = tid + 256*i decomposes as j4=u&1, lane=(u>>1)&63,
// kq=(u>>7)&7, mt=(u>>10)&1; element = h1[s = mt*16+(lane&15)]
// [k = kq*32+(lane>>4)*8+4*j4 .. +3]. LDS store address = base + 8*tid
// bytes -> conflict-free; global float4 reads cluster 64 B per sample.
// K-loop runs one n-tile at a time (peak live regs ~50: spill-proof).
// C/D layout: col(n)=lane&15, row(m)=(lane>>4)*4+reg [m89].
// ---------------------------------------------------------------------------
__global__ __launch_bounds__(256) void fc2_kernel(
    const int* __restrict__ g_idx,
    const _Float16* __restrict__ W2T, const float* __restrict__ b2,
    const int* __restrict__ wsi, const float* __restrict__ h1g,
    u16* __restrict__ h2g)
{
    __shared__ _Float16 afrag[2 * 2 * 8 * 64 * 8];   // [mt*2+h][kq][lane][8], 32 KB
    __shared__ int sb[GRPS];
    __shared__ int sG;

    const int tid = threadIdx.x;
    const int grp = blockIdx.x / NCT;
    const int tile = blockIdx.x % NCT;
    if (grp * GRPS >= wsi[0]) return;

    if (tid == 0) sG = g_idx[wsi[16 + grp * GRPS]];
    if (tid < GRPS) sb[tid] = wsi[16 + grp * GRPS + tid];
    __syncthreads();
    const _Float16* W2Tg = W2T + (size_t)sG * W2T_GSTRIDE;
    const float* b2g = b2 + sG * 1568;

    // ---- stage A fragments (hi/lo split), conflict-free stores ----
    {
        const float4* h1p4 = (const float4*)(h1g + (size_t)grp * 8192);
        #pragma unroll
        for (int i = 0; i < 8; ++i) {
            const int u = tid + 256 * i;
            const int j4 = u & 1;                  // j base = 4*j4
            const int lane = (u >> 1) & 63;
            const int kq = (u >> 7) & 7;
            const int mt = (u >> 10) & 1;
            const int s = mt * 16 + (lane & 15);
            const float4 v = h1p4[s * 64 + kq * 8 + ((lane >> 4) << 1) + j4];
            const float vv[4] = {v.x, v.y, v.z, v.w};
            f16x4 hi, lo;
            #pragma unroll
            for (int e = 0; e < 4; ++e) {
                hi[e] = (_Float16)vv[e];
                lo[e] = (_Float16)(vv[e] - (float)hi[e]);
            }
            const int bh = (((mt * 2 + 0) * 8 + kq) * 64 + lane) * 8 + 4 * j4;
            const int bl = (((mt * 2 + 1) * 8 + kq) * 64 + lane) * 8 + 4 * j4;
            *(f16x4*)&afrag[bh] = hi;   // addr = base + 8*tid bytes: conflict-free
            *(f16x4*)&afrag[bl] = lo;
        }
    }
    __syncthreads();

    const int wave = tid >> 6;
    const int lane = tid & 63;
    const int q = lane >> 4;
    const int nl = lane & 15;
    const int nb0 = tile * 128 + 2 * wave * 16;
    if (nb0 >= 1568) return;

    #pragma unroll
    for (int nt = 0; nt < 2; ++nt) {
        const int nb = nb0 + nt * 16;
        if (nb >= 1568) break;
        const int n = nb + nl;
        const _Float16* bp = W2Tg + (size_t)n * 256 + q * 8;
        f32x4 accA = {0.f, 0.f, 0.f, 0.f}, accB = accA;
        #pragma unroll
        for (int kq = 0; kq < 8; ++kq) {
            const f16x8 b = *(const f16x8*)(bp + kq * 32);
            const f16x8 a0h = *(const f16x8*)&afrag[((0 * 8 + kq) * 64 + lane) * 8];
            const f16x8 a0l = *(const f16x8*)&afrag[((1 * 8 + kq) * 64 + lane) * 8];
            const f16x8 a1h = *(const f16x8*)&afrag[((2 * 8 + kq) * 64 + lane) * 8];
            const f16x8 a1l = *(const f16x8*)&afrag[((3 * 8 + kq) * 64 + lane) * 8];
            accA = __builtin_amdgcn_mfma_f32_16x16x32_f16(a0h, b, accA, 0, 0, 0);
            accA = __builtin_amdgcn_mfma_f32_16x16x32_f16(a0l, b, accA, 0, 0, 0);
            accB = __builtin_amdgcn_mfma_f32_16x16x32_f16(a1h, b, accB, 0, 0, 0);
            accB = __builtin_amdgcn_mfma_f32_16x16x32_f16(a1l, b, accB, 0, 0, 0);
        }
        // epilogue for this n-tile
        const float bias = b2g[n];
        const int ci = n / 49, rm = n % 49;
        const int off = ci * 56 + (rm / 7) * 8 + (rm % 7);
        #pragma unroll
        for (int mt = 0; mt < 2; ++mt) {
            const f32x4 a = (mt == 0) ? accA : accB;
            #pragma unroll
            for (int reg = 0; reg < 4; ++reg) {
                const int s = mt * 16 + q * 4 + reg;
                const int bb = sb[s];
                if (bb >= 0)
                    h2g[(size_t)bb * H2_ELEMS + off] = f2bf(lrelu(a[reg] + bias));
            }
        }
    }
}

// ---------------------------------------------------------------------------
// conv2 half-pass (R10-proven): output x in [14*H, 14*H+14).
// ---------------------------------------------------------------------------
template <int H>
__device__ __forceinline__ void conv2_half(
    const float (*c1s)[14][20], u16 (*c2s)[28][30],
    const float* cw2g, const float bv, const int co, const int y)
{
    float acc[14];
    #pragma unroll
    for (int xx = 0; xx < 14; ++xx) acc[xx] = bv;
    const int a0 = (y + 1) & 1;
    for (int aa = 0; aa < 2; ++aa) {
        const int a = a0 + 2 * aa;
        const int iy = (y + 1 - a) >> 1;
        if ((unsigned)iy < 14u) {
            #pragma unroll 2
            for (int ci = 0; ci < 16; ++ci) {
                float rr[12];
                if (H == 0) {
                    *(float4*)&rr[0] = *(const float4*)&c1s[ci][iy][0];
                    *(float4*)&rr[4] = *(const float4*)&c1s[ci][iy][4];
                } else {
                    *(float4*)&rr[0] = *(const float4*)&c1s[ci][iy][4];
                    *(float4*)&rr[4] = *(const float4*)&c1s[ci][iy][8];
                    *(float4*)&rr[8] = *(const float4*)&c1s[ci][iy][12];
                }
                const float4 w4 = *(const float4*)(cw2g + ci * 128 + co * 16 + a * 4);
                const float wv[4] = {w4.x, w4.y, w4.z, w4.w};
                #pragma unroll
                for (int xx = 0; xx < 14; ++xx) {
                    const int x = 14 * H + xx;
                    const int c0v = (x + 1) & 1;
                    const int ix0 = (x + 1 - c0v) >> 1;
                    const int li = ix0 - 4 * H;
                    if (ix0 < 14) acc[xx] += rr[li] * wv[c0v];
                    if (ix0 >= 1) acc[xx] += rr[li - 1] * wv[c0v + 2];
                }
            }
        }
    }
    u32* dst = (u32*)&c2s[co][y][0];
    #pragma unroll
    for (int xx = 0; xx < 7; ++xx) {
        const u32 lo = f2bf(lrelu(acc[2 * xx]));
        const u32 hi = f2bf(lrelu(acc[2 * xx + 1]));
        dst[7 * H + xx] = lo | (hi << 16);
    }
}

// ---------------------------------------------------------------------------
// Kernel 4: all three transposed convs, ONE sample per block (R10-proven).
// LDS aliasing: c2s over dead h2s. ~31.4 KB, 5 blocks/CU.
// ---------------------------------------------------------------------------
__global__ __launch_bounds__(256, 5) void conv_kernel(
    const int* __restrict__ g_idx,
    const float* __restrict__ cw1, const float* __restrict__ cb1,
    const float* __restrict__ cw2, const float* __restrict__ cb2,
    const float* __restrict__ cw3, const float* __restrict__ cb3,
    const u16* __restrict__ h2g, float* __restrict__ out)
{
    __shared__ __align__(16) char smem[13440 + 17920];
    float (*h2s)[7][8]   = (float (*)[7][8])smem;            // [32][7][8]
    u16  (*c2s)[28][30]  = (u16 (*)[28][30])smem;            // [8][28][30]
    float (*c1s)[14][20] = (float (*)[14][20])(smem + 13440);
    __shared__ float w3s[72];

    const int tid = threadIdx.x;
    const int b = blockIdx.x;
    const int g = g_idx[b];
    const float* cw1g = cw1 + g * 8192;
    const float* cb1g = cb1 + g * 16;
    const float* cw2g = cw2 + g * 2048;
    const float* cb2g = cb2 + g * 8;
    const float* cw3g = cw3 + g * 72;
    const float  cb3v = cb3[g];

    if (tid < 224) {
        const uint4 qv = ((const uint4*)(h2g + (size_t)b * H2_ELEMS))[tid];
        float* hp = (float*)h2s + 8 * tid;
        ((float4*)hp)[0] = make_float4(bflo(qv.x), bfhi(qv.x), bflo(qv.y), bfhi(qv.y));
        ((float4*)hp)[1] = make_float4(bflo(qv.z), bfhi(qv.z), bflo(qv.w), bfhi(qv.w));
    }
    if (tid < 72) w3s[tid] = cw3g[tid];
    __syncthreads();

    // conv1: [32,7,7] -> [16,14,14], k=4, s=2
    if (tid < 224) {
        const int co = tid / 14, y = tid % 14;
        float acc[14];
        const float bv = cb1g[co];
        #pragma unroll
        for (int x = 0; x < 14; ++x) acc[x] = bv;
        const int a0 = (y + 1) & 1;
        for (int aa = 0; aa < 2; ++aa) {
            const int a = a0 + 2 * aa;
            const int iy = (y + 1 - a) >> 1;
            if ((unsigned)iy < 7u) {
                #pragma unroll 2
                for (int ci = 0; ci < 32; ++ci) {
                    float rr[8];
                    *(float4*)&rr[0] = *(const float4*)&h2s[ci][iy][0];
                    *(float4*)&rr[4] = *(const float4*)&h2s[ci][iy][4];
                    const float4 w4 = *(const float4*)(cw1g + ci * 256 + co * 16 + a * 4);
                    const float wv[4] = {w4.x, w4.y, w4.z, w4.w};
                    #pragma unroll
                    for (int x = 0; x < 14; ++x) {
                        const int c0v = (x + 1) & 1;
                        const int ix0 = (x + 1 - c0v) >> 1;
                        if (ix0 < 7)  acc[x] += rr[ix0] * wv[c0v];
                        if (ix0 >= 1) acc[x] += rr[ix0 - 1] * wv[c0v + 2];
                    }
                }
            }
        }
        #pragma unroll
        for (int x = 0; x < 14; ++x) acc[x] = lrelu(acc[x]);
        *(float4*)&c1s[co][y][0]  = *(float4*)&acc[0];
        *(float4*)&c1s[co][y][4]  = *(float4*)&acc[4];
        *(float4*)&c1s[co][y][8]  = *(float4*)&acc[8];
        *(float2*)&c1s[co][y][12] = *(float2*)&acc[12];
    }
    __syncthreads();   // h2s dead; c2s may be written

    if (tid < 224) {
        const int co = tid / 28, y = tid % 28;
        const float bv = cb2g[co];
        conv2_half<0>(c1s, c2s, cw2g, bv, co, y);
        conv2_half<1>(c1s, c2s, cw2g, bv, co, y);
    }
    __syncthreads();

    if (tid < 196) {
        const int y = tid / 7, qq = tid % 7;
        const int xb = qq * 4;
        float acc[4] = {cb3v, cb3v, cb3v, cb3v};
        for (int ci = 0; ci < 8; ++ci) {
            float wv[9];
            #pragma unroll
            for (int j = 0; j < 9; ++j) wv[j] = w3s[ci * 9 + j];
            #pragma unroll
            for (int a = 0; a < 3; ++a) {
                const int iy = y + 1 - a;
                if ((unsigned)iy < 28u) {
                    float rr[6];
                    #pragma unroll
                    for (int j = 0; j < 6; ++j) {
                        const int ix = xb - 1 + j;
                        rr[j] = ((unsigned)ix < 28u) ? bf1(c2s[ci][iy][ix]) : 0.f;
                    }
                    #pragma unroll
                    for (int xx = 0; xx < 4; ++xx)
                        #pragma unroll
                        for (int c = 0; c < 3; ++c)
                            acc[xx] += rr[xx + 2 - c] * wv[a * 3 + c];
                }
            }
        }
        float* op = out + (size_t)b * 784 + y * 28 + xb;
        #pragma unroll
        for (int xx = 0; xx < 4; ++xx) op[xx] = fast_tanh(acc[xx]);
    }
}

extern "C" void kernel_launch(void* const* d_in, const int* in_sizes, int n_in,
                              void* d_out, int out_size, void* d_ws, size_t ws_size,
                              hipStream_t stream) {
    const float* z   = (const float*)d_in[0];
    const int*   gi  = (const int*)d_in[1];
    const float* W1  = (const float*)d_in[2];
    const float* b1  = (const float*)d_in[3];
    const float* W2  = (const float*)d_in[4];
    const float* b2  = (const float*)d_in[5];
    const float* cw1 = (const float*)d_in[6];
    const float* cb1 = (const float*)d_in[7];
    const float* cw2 = (const float*)d_in[8];
    const float* cb2 = (const float*)d_in[9];
    const float* cw3 = (const float*)d_in[10];
    const float* cb3 = (const float*)d_in[11];
    int*      wsi = (int*)d_ws;
    float*    h1g = (float*)((char*)d_ws + WS_H1_OFF);
    u16*      h2g = (u16*)((char*)d_ws + WS_H2_OFF);
    _Float16* w2t = (_Float16*)((char*)d_ws + WS_W2T_OFF);

    bin_kernel<<<1, 256, 0, stream>>>(gi, wsi);
    prep_kernel<<<NB_W2T + MAXG * 4, 256, 0, stream>>>(z, gi, W1, b1, W2, wsi, h1g, w2t);
    fc2_kernel<<<MAXG * NCT, 256, 0, stream>>>(gi, w2t, b2, wsi, h1g, h2g);
    conv_kernel<<<BATCH, 256, 0, stream>>>(gi, cw1, cb1, cw2, cb2, cw3, cb3,
                                           h2g, (float*)d_out);
}